// Round 2
// baseline (1068.852 us; speedup 1.0000x reference)
//
#include <hip/hip_runtime.h>

#define NN 100000
#define EE 600000
#define HH 128
#define GG 1000
#define NPAD 100096   // 782 * 128
#define NBLK 782

// ---------------- CSR build ----------------
__global__ void k_zero_i32(int* __restrict__ p, int n){
    int i = blockIdx.x*256 + threadIdx.x;
    if (i < n) p[i] = 0;
}

__global__ void k_hist(const int* __restrict__ dst, int* __restrict__ cnt){
    int e = blockIdx.x*256 + threadIdx.x;
    if (e < EE) atomicAdd(&cnt[dst[e]], 1);
}

// block scans 1024 elements (256 threads x 4); exclusive result + block sum
__global__ void k_scan1(const int* __restrict__ cnt, int* __restrict__ excl,
                        int* __restrict__ bsums, int n){
    __shared__ int wsum[4];
    int t = threadIdx.x;
    int idx = blockIdx.x*1024 + t*4;
    int c[4];
#pragma unroll
    for (int i = 0; i < 4; i++) c[i] = (idx+i < n) ? cnt[idx+i] : 0;
    int s = c[0]+c[1]+c[2]+c[3];
    int lane = t & 63, w = t >> 6;
    int x = s;
#pragma unroll
    for (int off = 1; off < 64; off <<= 1){
        int y = __shfl_up(x, off);
        if (lane >= off) x += y;
    }
    if (lane == 63) wsum[w] = x;
    __syncthreads();
    int woff = 0;
    for (int i = 0; i < w; i++) woff += wsum[i];
    int run = woff + x - s;   // exclusive prefix of this thread
#pragma unroll
    for (int i = 0; i < 4; i++){
        if (idx+i < n) excl[idx+i] = run;
        run += c[i];
    }
    if (t == 255) bsums[blockIdx.x] = woff + x;
}

// single block, exclusive scan of block sums (nb <= 128)
__global__ void k_scan2(int* __restrict__ bsums, int nb){
    __shared__ int ws2[2];
    int t = threadIdx.x;
    int v = (t < nb) ? bsums[t] : 0;
    int lane = t & 63, w = t >> 6;
    int x = v;
#pragma unroll
    for (int off = 1; off < 64; off <<= 1){
        int y = __shfl_up(x, off);
        if (lane >= off) x += y;
    }
    if (lane == 63) ws2[w] = x;
    __syncthreads();
    int off0 = (w == 1) ? ws2[0] : 0;
    if (t < nb) bsums[t] = off0 + x - v;
}

__global__ void k_scan3(int* __restrict__ rp, const int* __restrict__ bsums,
                        int* __restrict__ fill, int n){
    int i = blockIdx.x*256 + threadIdx.x;
    if (i < n){
        int r = rp[i] + bsums[i >> 10];
        rp[i] = r;
        fill[i] = r;
    }
    if (i == 0) rp[n] = EE;
}

__global__ void k_place(const int* __restrict__ src, const int* __restrict__ dst,
                        int* __restrict__ fill, int* __restrict__ ssrc){
    int e = blockIdx.x*256 + threadIdx.x;
    if (e < EE){
        int p = atomicAdd(&fill[dst[e]], 1);
        ssrc[p] = src[e];
    }
}

// ---------------- layer 0 (in=3) ----------------
__global__ void k_agg3(const float* __restrict__ x, const int* __restrict__ rp,
                       const int* __restrict__ ssrc, float* __restrict__ y){
    int i = blockIdx.x*256 + threadIdx.x;
    if (i >= NN) return;
    float a0 = x[3*i], a1 = x[3*i+1], a2 = x[3*i+2];
    int b = rp[i], e = rp[i+1];
    for (int k = b; k < e; k++){
        int s = ssrc[k];
        a0 += x[3*s]; a1 += x[3*s+1]; a2 += x[3*s+2];
    }
    y[3*i] = a0; y[3*i+1] = a1; y[3*i+2] = a2;
}

__global__ void k_mlp0(const float* __restrict__ y0, const float* __restrict__ W1,
                       const float* __restrict__ b1, const float* __restrict__ g,
                       const float* __restrict__ be, const float* __restrict__ m,
                       const float* __restrict__ v, float* __restrict__ out){
    int idx = blockIdx.x*256 + threadIdx.x;
    if (idx >= NN*HH) return;
    int i = idx >> 7, j = idx & 127;
    float acc = b1[j] + y0[3*i]*W1[j] + y0[3*i+1]*W1[HH+j] + y0[3*i+2]*W1[2*HH+j];
    float r = rsqrtf(v[j] + 1e-5f);
    acc = g[j]*(acc - m[j])*r + be[j];
    out[idx] = fmaxf(acc, 0.f);
}

// ---------------- aggregation (H=128): y[i] = h[i] + sum_{e in CSR[i]} h[src_e]
__global__ void k_agg(const float* __restrict__ h, const int* __restrict__ rp,
                      const int* __restrict__ ssrc, float* __restrict__ y){
    int node = blockIdx.x*8 + (threadIdx.x >> 5);
    if (node >= NN) return;
    int c = (threadIdx.x & 31) << 2;
    float4 a = *(const float4*)&h[(size_t)node*HH + c];
    int b = rp[node], e = rp[node+1];
    for (int k = b; k < e; k++){
        int s = ssrc[k];
        const float4 t = *(const float4*)&h[(size_t)s*HH + c];
        a.x += t.x; a.y += t.y; a.z += t.z; a.w += t.w;
    }
    *(float4*)&y[(size_t)node*HH + c] = a;
}

// ---------------- fp32 GEMM [NPAD,128] @ [128,128], fused bias/BN/ReLU ----------
// block 128 threads, tile 128 rows x 128 cols, thread 8 rows x 16 cols,
// K chunked by 32.
// sA: pitch 34 + 4-float skew per 8-row group -> 8 broadcast addrs hit banks
//     {0,20,8,28,16,4,24,12} (conflict-free).
// sW: pitch 160, column-group uu (8 cols) at 10*uu -> disjoint (10*uu+7<160),
//     group bases 10*uu%32 all-distinct; per-instruction broadcast addrs
//     20*tx%32 (+10) are 8 distinct banks (conflict-free).
__launch_bounds__(128, 2)
__global__ void k_gemm(const float* __restrict__ A, const float* __restrict__ W,
                       const float* __restrict__ bias, const float* __restrict__ g,
                       const float* __restrict__ be, const float* __restrict__ m,
                       const float* __restrict__ v, int use_bn,
                       float* __restrict__ out){
    __shared__ __align__(16) float sA[4416];
    __shared__ __align__(16) float sW[5120];
    const int t = threadIdx.x;
    const int R0 = blockIdx.x << 7;
    const int tx = t & 7, ty = t >> 3;
    const int j0 = tx << 4, r0 = ty << 3;

    float acc[8][16];
#pragma unroll
    for (int i = 0; i < 8; i++)
#pragma unroll
        for (int j = 0; j < 16; j++) acc[i][j] = 0.f;

    const int u0 = j0 >> 3, u1 = u0 + 1;
    const int cA = 10*u0;
    const int cB = 10*u1;
    const int aBase = r0*34 + (ty << 2);

    for (int k0 = 0; k0 < HH; k0 += 32){
        // stage A tile chunk: 128 rows x 32 k
#pragma unroll
        for (int p = 0; p < 8; p++){
            int f = p*128 + t;            // 0..1023 float4 index
            int r = f >> 3, kk = (f & 7) << 2;
            float4 d = *(const float4*)&A[(size_t)(R0+r)*HH + k0 + kk];
            int sb = r*34 + ((r >> 3) << 2) + kk;
            sA[sb] = d.x; sA[sb+1] = d.y; sA[sb+2] = d.z; sA[sb+3] = d.w;
        }
        // stage W chunk: 32 k x 128 cols (group-strided layout)
#pragma unroll
        for (int p = 0; p < 8; p++){
            int f = p*128 + t;
            int k = f >> 5, jq = (f & 31) << 2;
            float4 d = *(const float4*)&W[(size_t)(k0+k)*HH + jq];
            int uu = jq >> 3;
            int pos = k*160 + 10*uu + (jq & 7);
            sW[pos] = d.x; sW[pos+1] = d.y; sW[pos+2] = d.z; sW[pos+3] = d.w;
        }
        __syncthreads();

#pragma unroll 2
        for (int kc = 0; kc < 32; kc += 2){
            float2 a[8];
#pragma unroll
            for (int ri = 0; ri < 8; ri++)
                a[ri] = *(const float2*)&sA[aBase + ri*34 + kc];
            float w0[16], w1[16];
            const int rb0 = kc*160, rb1 = rb0 + 160;
#pragma unroll
            for (int ci = 0; ci < 4; ci++){
                *(float2*)&w0[ci*2]     = *(const float2*)&sW[rb0 + cA + ci*2];
                *(float2*)&w0[8+ci*2]   = *(const float2*)&sW[rb0 + cB + ci*2];
                *(float2*)&w1[ci*2]     = *(const float2*)&sW[rb1 + cA + ci*2];
                *(float2*)&w1[8+ci*2]   = *(const float2*)&sW[rb1 + cB + ci*2];
            }
#pragma unroll
            for (int ri = 0; ri < 8; ri++){
                float ax = a[ri].x, ay = a[ri].y;
#pragma unroll
                for (int c = 0; c < 16; c++){
                    acc[ri][c] = fmaf(ax, w0[c], acc[ri][c]);
                    acc[ri][c] = fmaf(ay, w1[c], acc[ri][c]);
                }
            }
        }
        __syncthreads();
    }

    // epilogue: out = relu(sc*acc + sh)
    float sc[16], sh[16];
#pragma unroll
    for (int c = 0; c < 16; c++){
        int j = j0 + c;
        if (use_bn){
            float rr = rsqrtf(v[j] + 1e-5f);
            float gg = g[j]*rr;
            sc[c] = gg;
            sh[c] = be[j] + gg*(bias[j] - m[j]);
        } else {
            sc[c] = 1.f;
            sh[c] = bias[j];
        }
    }
#pragma unroll
    for (int ri = 0; ri < 8; ri++){
        int row = R0 + r0 + ri;
        float o[16];
#pragma unroll
        for (int c = 0; c < 16; c++)
            o[c] = fmaxf(fmaf(acc[ri][c], sc[c], sh[c]), 0.f);
        float4* d4 = (float4*)&out[(size_t)row*HH + j0];
        d4[0] = *(float4*)&o[0];  d4[1] = *(float4*)&o[4];
        d4[2] = *(float4*)&o[8];  d4[3] = *(float4*)&o[12];
    }
}

// ---------------- pooling + classifier ----------------
__global__ void k_out_init(float* __restrict__ out, const float* __restrict__ bc){
    int i = blockIdx.x*256 + threadIdx.x;
    if (i < GG) out[i] = bc[0];
}

__global__ void k_pool(const float* __restrict__ h, const float* __restrict__ Wc,
                       const int* __restrict__ batch, float* __restrict__ out){
    int node = blockIdx.x*4 + (threadIdx.x >> 6);
    int lane = threadIdx.x & 63;
    if (node >= NN) return;
    const float* hr = &h[(size_t)node*HH];
    float s = hr[lane]*Wc[lane] + hr[lane+64]*Wc[lane+64];
#pragma unroll
    for (int off = 32; off > 0; off >>= 1) s += __shfl_down(s, off);
    if (lane == 0) atomicAdd(&out[batch[node]], s);
}

extern "C" void kernel_launch(void* const* d_in, const int* in_sizes, int n_in,
                              void* d_out, int out_size, void* d_ws, size_t ws_size,
                              hipStream_t stream){
    const float* x     = (const float*)d_in[0];
    const int*   ei    = (const int*)d_in[1];
    const int*   batch = (const int*)d_in[2];
    const float* W1_0  = (const float*)d_in[3];
    const float* b1_0  = (const float*)d_in[4];
    const float* g_0   = (const float*)d_in[5];
    const float* be_0  = (const float*)d_in[6];
    const float* m_0   = (const float*)d_in[7];
    const float* v_0   = (const float*)d_in[8];
    const float* W2_0  = (const float*)d_in[9];
    const float* b2_0  = (const float*)d_in[10];
    const float* W1s   = (const float*)d_in[11];
    const float* b1s   = (const float*)d_in[12];
    const float* gs    = (const float*)d_in[13];
    const float* bes   = (const float*)d_in[14];
    const float* ms    = (const float*)d_in[15];
    const float* vs    = (const float*)d_in[16];
    const float* W2s   = (const float*)d_in[17];
    const float* b2s   = (const float*)d_in[18];
    const float* Wc    = (const float*)d_in[19];
    const float* bc    = (const float*)d_in[20];

    float* P0 = (float*)d_ws;
    float* P1 = P0 + (size_t)NPAD*HH;
    int* rp    = (int*)(P1 + (size_t)NPAD*HH);
    int* fill  = rp + (NN + 1);
    int* ssrc  = fill + NN;
    int* bsums = ssrc + EE;

    const int* src = ei;
    const int* dst = ei + EE;

    // --- CSR build (once per call, reused by all 5 layers) ---
    k_zero_i32<<<(NN+255)/256, 256, 0, stream>>>(fill, NN);
    k_hist<<<(EE+255)/256, 256, 0, stream>>>(dst, fill);
    k_scan1<<<98, 256, 0, stream>>>(fill, rp, bsums, NN);
    k_scan2<<<1, 128, 0, stream>>>(bsums, 98);
    k_scan3<<<(NN+255)/256, 256, 0, stream>>>(rp, bsums, fill, NN);
    k_place<<<(EE+255)/256, 256, 0, stream>>>(src, dst, fill, ssrc);

    // --- layer 0 (in=3) ---
    k_agg3<<<(NN+255)/256, 256, 0, stream>>>(x, rp, ssrc, P0);
    k_mlp0<<<(NN*HH)/256, 256, 0, stream>>>(P0, W1_0, b1_0, g_0, be_0, m_0, v_0, P1);
    k_gemm<<<NBLK, 128, 0, stream>>>(P1, W2_0, b2_0, nullptr, nullptr, nullptr, nullptr, 0, P0);

    // --- layers 1..4 ---
    float* cur = P0; float* oth = P1;
    for (int l = 0; l < 4; l++){
        k_agg<<<(NN+7)/8, 256, 0, stream>>>(cur, rp, ssrc, oth);
        k_gemm<<<NBLK, 128, 0, stream>>>(oth, W1s + (size_t)l*HH*HH, b1s + l*HH,
                                         gs + l*HH, bes + l*HH, ms + l*HH, vs + l*HH,
                                         1, cur);
        k_gemm<<<NBLK, 128, 0, stream>>>(cur, W2s + (size_t)l*HH*HH, b2s + l*HH,
                                         nullptr, nullptr, nullptr, nullptr, 0, oth);
        float* tmp = cur; cur = oth; oth = tmp;
    }

    // --- pooling + linear classifier (fused: out[g] = bc + sum_i dot(h_i, Wc)) ---
    k_out_init<<<(GG+255)/256, 256, 0, stream>>>((float*)d_out, bc);
    k_pool<<<(NN+3)/4, 256, 0, stream>>>(cur, Wc, batch, (float*)d_out);
}

// Round 3
// 708.104 us; speedup vs baseline: 1.5095x; 1.5095x over previous
//
#include <hip/hip_runtime.h>

#define NN 100000
#define EE 600000
#define HH 128
#define GG 1000
#define NPAD 100096   // 782 * 128
#define NBLK 782

typedef __attribute__((ext_vector_type(8))) short bf16x8;
typedef __attribute__((ext_vector_type(4))) float f32x4;

__device__ inline short f2bf(float x){
    unsigned u = __float_as_uint(x);
    unsigned r = (u + 0x7FFFu + ((u >> 16) & 1u)) >> 16;
    return (short)r;
}
__device__ inline float bf2f(short h){
    unsigned u = ((unsigned)(unsigned short)h) << 16;
    return __uint_as_float(u);
}

// ---------------- CSR build ----------------
__global__ void k_zero_i32(int* __restrict__ p, int n){
    int i = blockIdx.x*256 + threadIdx.x;
    if (i < n) p[i] = 0;
}

__global__ void k_hist(const int* __restrict__ dst, int* __restrict__ cnt){
    int e = blockIdx.x*256 + threadIdx.x;
    if (e < EE) atomicAdd(&cnt[dst[e]], 1);
}

__global__ void k_scan1(const int* __restrict__ cnt, int* __restrict__ excl,
                        int* __restrict__ bsums, int n){
    __shared__ int wsum[4];
    int t = threadIdx.x;
    int idx = blockIdx.x*1024 + t*4;
    int c[4];
#pragma unroll
    for (int i = 0; i < 4; i++) c[i] = (idx+i < n) ? cnt[idx+i] : 0;
    int s = c[0]+c[1]+c[2]+c[3];
    int lane = t & 63, w = t >> 6;
    int x = s;
#pragma unroll
    for (int off = 1; off < 64; off <<= 1){
        int y = __shfl_up(x, off);
        if (lane >= off) x += y;
    }
    if (lane == 63) wsum[w] = x;
    __syncthreads();
    int woff = 0;
    for (int i = 0; i < w; i++) woff += wsum[i];
    int run = woff + x - s;
#pragma unroll
    for (int i = 0; i < 4; i++){
        if (idx+i < n) excl[idx+i] = run;
        run += c[i];
    }
    if (t == 255) bsums[blockIdx.x] = woff + x;
}

__global__ void k_scan2(int* __restrict__ bsums, int nb){
    __shared__ int ws2[2];
    int t = threadIdx.x;
    int v = (t < nb) ? bsums[t] : 0;
    int lane = t & 63, w = t >> 6;
    int x = v;
#pragma unroll
    for (int off = 1; off < 64; off <<= 1){
        int y = __shfl_up(x, off);
        if (lane >= off) x += y;
    }
    if (lane == 63) ws2[w] = x;
    __syncthreads();
    int off0 = (w == 1) ? ws2[0] : 0;
    if (t < nb) bsums[t] = off0 + x - v;
}

__global__ void k_scan3(int* __restrict__ rp, const int* __restrict__ bsums,
                        int* __restrict__ fill, int n){
    int i = blockIdx.x*256 + threadIdx.x;
    if (i < n){
        int r = rp[i] + bsums[i >> 10];
        rp[i] = r;
        fill[i] = r;
    }
    if (i == 0) rp[n] = EE;
}

__global__ void k_place(const int* __restrict__ src, const int* __restrict__ dst,
                        int* __restrict__ fill, int* __restrict__ ssrc){
    int e = blockIdx.x*256 + threadIdx.x;
    if (e < EE){
        int p = atomicAdd(&fill[dst[e]], 1);
        ssrc[p] = src[e];
    }
}

// ---------------- graph rowptr from sorted batch ----------------
__global__ void k_bounds(const int* __restrict__ batch, int* __restrict__ rp_g){
    int i = blockIdx.x*256 + threadIdx.x;
    if (i >= NN) return;
    int b = batch[i];
    if (i == 0){
        for (int g = 0; g <= b; g++) rp_g[g] = 0;
    } else {
        int p = batch[i-1];
        for (int g = p+1; g <= b; g++) rp_g[g] = i;
    }
    if (i == NN-1){
        for (int g = b+1; g <= GG; g++) rp_g[g] = NN;
    }
}

// ---------------- W pre-swizzle into bf16 hi/lo B-fragment order ----------
// Wp[m] layout: plane p in {hi=0,lo=1}; idx = ((p*32 + kc*8 + ct)*64 + l)*8 + j
// value = W[kc*32 + (l>>4)*8 + j][ct*16 + (l&15)]
__global__ void k_wprep(const float* __restrict__ W2_0, const float* __restrict__ W1s,
                        const float* __restrict__ W2s, short* __restrict__ Wp){
    int tid = blockIdx.x*256 + threadIdx.x;
    if (tid >= 9*16384) return;
    int m = tid >> 14;
    int r = tid & 16383;
    int j = r & 7, l = (r >> 3) & 63, ctkc = r >> 9;
    int ct = ctkc & 7, kc = ctkc >> 3;
    int k = kc*32 + ((l >> 4) << 3) + j;
    int n = (ct << 4) + (l & 15);
    const float* W = (m == 0) ? W2_0
                   : (m <= 4) ? (W1s + (size_t)(m-1)*HH*HH)
                              : (W2s + (size_t)(m-5)*HH*HH);
    float w = W[k*HH + n];
    short hi = f2bf(w);
    short lo = f2bf(w - bf2f(hi));
    short* base = Wp + (size_t)m*32768;
    base[r] = hi;
    base[16384 + r] = lo;
}

// ---------------- layer 0 (in=3) ----------------
__global__ void k_agg3(const float* __restrict__ x, const int* __restrict__ rp,
                       const int* __restrict__ ssrc, float* __restrict__ y){
    int i = blockIdx.x*256 + threadIdx.x;
    if (i >= NN) return;
    float a0 = x[3*i], a1 = x[3*i+1], a2 = x[3*i+2];
    int b = rp[i], e = rp[i+1];
    for (int k = b; k < e; k++){
        int s = ssrc[k];
        a0 += x[3*s]; a1 += x[3*s+1]; a2 += x[3*s+2];
    }
    y[3*i] = a0; y[3*i+1] = a1; y[3*i+2] = a2;
}

__global__ void k_mlp0(const float* __restrict__ y0, const float* __restrict__ W1,
                       const float* __restrict__ b1, const float* __restrict__ g,
                       const float* __restrict__ be, const float* __restrict__ m,
                       const float* __restrict__ v, float* __restrict__ out){
    int idx = blockIdx.x*256 + threadIdx.x;
    if (idx >= NN*HH) return;
    int i = idx >> 7, j = idx & 127;
    float acc = b1[j] + y0[3*i]*W1[j] + y0[3*i+1]*W1[HH+j] + y0[3*i+2]*W1[2*HH+j];
    float r = rsqrtf(v[j] + 1e-5f);
    acc = g[j]*(acc - m[j])*r + be[j];
    out[idx] = fmaxf(acc, 0.f);
}

// ---------------- aggregation: y[i] = h[i] + sum_{e in CSR[i]} h[src_e]
__global__ void k_agg(const float* __restrict__ h, const int* __restrict__ rp,
                      const int* __restrict__ ssrc, float* __restrict__ y){
    int node = blockIdx.x*8 + (threadIdx.x >> 5);
    if (node >= NN) return;
    int c = (threadIdx.x & 31) << 2;
    float4 a = *(const float4*)&h[(size_t)node*HH + c];
    int b = rp[node], e = rp[node+1];
    for (int k = b; k < e; k++){
        int s = ssrc[k];
        const float4 t = *(const float4*)&h[(size_t)s*HH + c];
        a.x += t.x; a.y += t.y; a.z += t.z; a.w += t.w;
    }
    *(float4*)&y[(size_t)node*HH + c] = a;
}

// ---------------- MFMA bf16x3 GEMM [NPAD,128] @ [128,128] + bias/BN/ReLU -----
// block 256 = 4 waves; wave handles 32 rows x 128 cols.
// A frag (verified layout): lane l holds A[m=l&15][k=(l>>4)*8+j]
// B frag: lane l holds W[k=(l>>4)*8+j][n=l&15] -- pre-swizzled in Wp
// D frag (verified): col=l&15, row=(l>>4)*4+r
__global__ void k_gemm_mfma(const float* __restrict__ A, const short* __restrict__ Wp,
                            const float* __restrict__ bias, const float* __restrict__ g,
                            const float* __restrict__ be, const float* __restrict__ m,
                            const float* __restrict__ v, int use_bn,
                            float* __restrict__ out){
    int t = threadIdx.x;
    int l = t & 63, w = t >> 6;
    int n = l & 15, q = l >> 4;
    int R = blockIdx.x*128 + w*32;

    const float* a0p = A + (size_t)(R + n)*HH + q*8;
    const float* a1p = a0p + (size_t)16*HH;
    const short* Wh = Wp;
    const short* Wl = Wp + 16384;

    f32x4 acc[2][8];
#pragma unroll
    for (int rt = 0; rt < 2; rt++)
#pragma unroll
        for (int ct = 0; ct < 8; ct++) acc[rt][ct] = (f32x4){0.f,0.f,0.f,0.f};

#pragma unroll
    for (int kc = 0; kc < 4; kc++){
        float4 f0a = *(const float4*)(a0p + kc*32);
        float4 f0b = *(const float4*)(a0p + kc*32 + 4);
        float4 f1a = *(const float4*)(a1p + kc*32);
        float4 f1b = *(const float4*)(a1p + kc*32 + 4);
        float x0[8] = {f0a.x,f0a.y,f0a.z,f0a.w,f0b.x,f0b.y,f0b.z,f0b.w};
        float x1[8] = {f1a.x,f1a.y,f1a.z,f1a.w,f1b.x,f1b.y,f1b.z,f1b.w};
        bf16x8 ah0, al0, ah1, al1;
#pragma unroll
        for (int i = 0; i < 8; i++){
            short h0 = f2bf(x0[i]); ah0[i] = h0; al0[i] = f2bf(x0[i] - bf2f(h0));
            short h1 = f2bf(x1[i]); ah1[i] = h1; al1[i] = f2bf(x1[i] - bf2f(h1));
        }
        const short* ph = Wh + (size_t)(kc*8)*512 + l*8;
        const short* pl = Wl + (size_t)(kc*8)*512 + l*8;
#pragma unroll
        for (int ct = 0; ct < 8; ct++){
            bf16x8 bh = *(const bf16x8*)(ph + ct*512);
            bf16x8 bl = *(const bf16x8*)(pl + ct*512);
            acc[0][ct] = __builtin_amdgcn_mfma_f32_16x16x32_bf16(ah0, bh, acc[0][ct], 0, 0, 0);
            acc[1][ct] = __builtin_amdgcn_mfma_f32_16x16x32_bf16(ah1, bh, acc[1][ct], 0, 0, 0);
            acc[0][ct] = __builtin_amdgcn_mfma_f32_16x16x32_bf16(al0, bh, acc[0][ct], 0, 0, 0);
            acc[1][ct] = __builtin_amdgcn_mfma_f32_16x16x32_bf16(al1, bh, acc[1][ct], 0, 0, 0);
            acc[0][ct] = __builtin_amdgcn_mfma_f32_16x16x32_bf16(ah0, bl, acc[0][ct], 0, 0, 0);
            acc[1][ct] = __builtin_amdgcn_mfma_f32_16x16x32_bf16(ah1, bl, acc[1][ct], 0, 0, 0);
        }
    }

    // epilogue: out = relu(sc*acc + sh)
#pragma unroll
    for (int ct = 0; ct < 8; ct++){
        int j = (ct << 4) + n;
        float scv, shv;
        if (use_bn){
            float rr = rsqrtf(v[j] + 1e-5f);
            float gg = g[j]*rr;
            scv = gg;
            shv = be[j] + gg*(bias[j] - m[j]);
        } else {
            scv = 1.f;
            shv = bias[j];
        }
#pragma unroll
        for (int rt = 0; rt < 2; rt++){
#pragma unroll
            for (int r = 0; r < 4; r++){
                int row = R + rt*16 + q*4 + r;
                out[(size_t)row*HH + j] = fmaxf(fmaf(acc[rt][ct][r], scv, shv), 0.f);
            }
        }
    }
}

// ---------------- pooling + classifier: block per graph, no atomics ---------
__global__ void k_pool2(const float* __restrict__ h, const float* __restrict__ Wc,
                        const float* __restrict__ bc, const int* __restrict__ rp_g,
                        float* __restrict__ out){
    __shared__ float ws[4];
    int g = blockIdx.x, t = threadIdx.x;
    long beg = (long)rp_g[g]*HH, end = (long)rp_g[g+1]*HH;
    float s = 0.f;
    for (long i = beg + t; i < end; i += 256) s += h[i]*Wc[(int)(i & 127)];
    int lane = t & 63, w = t >> 6;
#pragma unroll
    for (int off = 32; off > 0; off >>= 1) s += __shfl_down(s, off);
    if (lane == 0) ws[w] = s;
    __syncthreads();
    if (t == 0) out[g] = bc[0] + ws[0] + ws[1] + ws[2] + ws[3];
}

extern "C" void kernel_launch(void* const* d_in, const int* in_sizes, int n_in,
                              void* d_out, int out_size, void* d_ws, size_t ws_size,
                              hipStream_t stream){
    const float* x     = (const float*)d_in[0];
    const int*   ei    = (const int*)d_in[1];
    const int*   batch = (const int*)d_in[2];
    const float* W1_0  = (const float*)d_in[3];
    const float* b1_0  = (const float*)d_in[4];
    const float* g_0   = (const float*)d_in[5];
    const float* be_0  = (const float*)d_in[6];
    const float* m_0   = (const float*)d_in[7];
    const float* v_0   = (const float*)d_in[8];
    const float* W2_0  = (const float*)d_in[9];
    const float* b2_0  = (const float*)d_in[10];
    const float* W1s   = (const float*)d_in[11];
    const float* b1s   = (const float*)d_in[12];
    const float* gs    = (const float*)d_in[13];
    const float* bes   = (const float*)d_in[14];
    const float* ms    = (const float*)d_in[15];
    const float* vs    = (const float*)d_in[16];
    const float* W2s   = (const float*)d_in[17];
    const float* b2s   = (const float*)d_in[18];
    const float* Wc    = (const float*)d_in[19];
    const float* bc    = (const float*)d_in[20];

    float* P0 = (float*)d_ws;
    float* P1 = P0 + (size_t)NPAD*HH;
    int* rp    = (int*)(P1 + (size_t)NPAD*HH);
    int* fill  = rp + (NN + 1);
    int* ssrc  = fill + NN;
    int* bsums = ssrc + EE;
    int* rp_g  = bsums + 128;
    // 16B-align Wp
    size_t wp_off = (size_t)(rp_g + (GG + 1) - (int*)d_ws);   // in ints
    wp_off = (wp_off + 3) & ~(size_t)3;                       // 16B boundary in ints
    short* Wp = (short*)((int*)d_ws + wp_off);

    const int* src = ei;
    const int* dst = ei + EE;

    // --- CSR build ---
    k_zero_i32<<<(NN+255)/256, 256, 0, stream>>>(fill, NN);
    k_hist<<<(EE+255)/256, 256, 0, stream>>>(dst, fill);
    k_scan1<<<98, 256, 0, stream>>>(fill, rp, bsums, NN);
    k_scan2<<<1, 128, 0, stream>>>(bsums, 98);
    k_scan3<<<(NN+255)/256, 256, 0, stream>>>(rp, bsums, fill, NN);
    k_place<<<(EE+255)/256, 256, 0, stream>>>(src, dst, fill, ssrc);

    // --- graph rowptr + weight pre-swizzle ---
    k_bounds<<<(NN+255)/256, 256, 0, stream>>>(batch, rp_g);
    k_wprep<<<(9*16384)/256, 256, 0, stream>>>(W2_0, W1s, W2s, Wp);

    // --- layer 0 (in=3) ---
    k_agg3<<<(NN+255)/256, 256, 0, stream>>>(x, rp, ssrc, P0);
    k_mlp0<<<(NN*HH)/256, 256, 0, stream>>>(P0, W1_0, b1_0, g_0, be_0, m_0, v_0, P1);
    k_gemm_mfma<<<NBLK, 256, 0, stream>>>(P1, Wp, b2_0,
                                          nullptr, nullptr, nullptr, nullptr, 0, P0);

    // --- layers 1..4 ---
    float* cur = P0; float* oth = P1;
    for (int l = 0; l < 4; l++){
        k_agg<<<(NN+7)/8, 256, 0, stream>>>(cur, rp, ssrc, oth);
        k_gemm_mfma<<<NBLK, 256, 0, stream>>>(oth, Wp + (size_t)(1+l)*32768, b1s + l*HH,
                                              gs + l*HH, bes + l*HH, ms + l*HH, vs + l*HH,
                                              1, cur);
        k_gemm_mfma<<<NBLK, 256, 0, stream>>>(cur, Wp + (size_t)(5+l)*32768, b2s + l*HH,
                                              nullptr, nullptr, nullptr, nullptr, 0, oth);
        float* tmp = cur; cur = oth; oth = tmp;
    }

    // --- pooling + classifier (no atomics) ---
    k_pool2<<<GG, 256, 0, stream>>>(cur, Wc, bc, rp_g, (float*)d_out);
}

// Round 4
// 659.508 us; speedup vs baseline: 1.6207x; 1.0737x over previous
//
#include <hip/hip_runtime.h>

#define NN 100000
#define EE 600000
#define HH 128
#define GG 1000
#define NPAD 100096   // 782 * 128
#define NBLK 782

typedef __attribute__((ext_vector_type(8))) short bf16x8;
typedef __attribute__((ext_vector_type(4))) float f32x4;

__device__ inline short f2bf(float x){
    unsigned u = __float_as_uint(x);
    unsigned r = (u + 0x7FFFu + ((u >> 16) & 1u)) >> 16;
    return (short)r;
}
__device__ inline float bf2f(short h){
    unsigned u = ((unsigned)(unsigned short)h) << 16;
    return __uint_as_float(u);
}

// ---------------- CSR build ----------------
__global__ void k_zero_i32(int* __restrict__ p, int n){
    int i = blockIdx.x*256 + threadIdx.x;
    if (i < n) p[i] = 0;
}

__global__ void k_hist(const int* __restrict__ dst, int* __restrict__ cnt){
    int e = blockIdx.x*256 + threadIdx.x;
    if (e < EE) atomicAdd(&cnt[dst[e]], 1);
}

__global__ void k_scan1(const int* __restrict__ cnt, int* __restrict__ excl,
                        int* __restrict__ bsums, int n){
    __shared__ int wsum[4];
    int t = threadIdx.x;
    int idx = blockIdx.x*1024 + t*4;
    int c[4];
#pragma unroll
    for (int i = 0; i < 4; i++) c[i] = (idx+i < n) ? cnt[idx+i] : 0;
    int s = c[0]+c[1]+c[2]+c[3];
    int lane = t & 63, w = t >> 6;
    int x = s;
#pragma unroll
    for (int off = 1; off < 64; off <<= 1){
        int y = __shfl_up(x, off);
        if (lane >= off) x += y;
    }
    if (lane == 63) wsum[w] = x;
    __syncthreads();
    int woff = 0;
    for (int i = 0; i < w; i++) woff += wsum[i];
    int run = woff + x - s;
#pragma unroll
    for (int i = 0; i < 4; i++){
        if (idx+i < n) excl[idx+i] = run;
        run += c[i];
    }
    if (t == 255) bsums[blockIdx.x] = woff + x;
}

__global__ void k_scan2(int* __restrict__ bsums, int nb){
    __shared__ int ws2[2];
    int t = threadIdx.x;
    int v = (t < nb) ? bsums[t] : 0;
    int lane = t & 63, w = t >> 6;
    int x = v;
#pragma unroll
    for (int off = 1; off < 64; off <<= 1){
        int y = __shfl_up(x, off);
        if (lane >= off) x += y;
    }
    if (lane == 63) ws2[w] = x;
    __syncthreads();
    int off0 = (w == 1) ? ws2[0] : 0;
    if (t < nb) bsums[t] = off0 + x - v;
}

__global__ void k_scan3(int* __restrict__ rp, const int* __restrict__ bsums,
                        int* __restrict__ fill, int n){
    int i = blockIdx.x*256 + threadIdx.x;
    if (i < n){
        int r = rp[i] + bsums[i >> 10];
        rp[i] = r;
        fill[i] = r;
    }
    if (i == 0) rp[n] = EE;
}

__global__ void k_place(const int* __restrict__ src, const int* __restrict__ dst,
                        int* __restrict__ fill, int* __restrict__ ssrc){
    int e = blockIdx.x*256 + threadIdx.x;
    if (e < EE){
        int p = atomicAdd(&fill[dst[e]], 1);
        ssrc[p] = src[e];
    }
}

// ---------------- graph rowptr from sorted batch ----------------
__global__ void k_bounds(const int* __restrict__ batch, int* __restrict__ rp_g){
    int i = blockIdx.x*256 + threadIdx.x;
    if (i >= NN) return;
    int b = batch[i];
    if (i == 0){
        for (int g = 0; g <= b; g++) rp_g[g] = 0;
    } else {
        int p = batch[i-1];
        for (int g = p+1; g <= b; g++) rp_g[g] = i;
    }
    if (i == NN-1){
        for (int g = b+1; g <= GG; g++) rp_g[g] = NN;
    }
}

// ---------------- W pre-swizzle into bf16 hi/lo B-fragment order ----------
__global__ void k_wprep(const float* __restrict__ W2_0, const float* __restrict__ W1s,
                        const float* __restrict__ W2s, short* __restrict__ Wp){
    int tid = blockIdx.x*256 + threadIdx.x;
    if (tid >= 9*16384) return;
    int m = tid >> 14;
    int r = tid & 16383;
    int j = r & 7, l = (r >> 3) & 63, ctkc = r >> 9;
    int ct = ctkc & 7, kc = ctkc >> 3;
    int k = kc*32 + ((l >> 4) << 3) + j;
    int n = (ct << 4) + (l & 15);
    const float* W = (m == 0) ? W2_0
                   : (m <= 4) ? (W1s + (size_t)(m-1)*HH*HH)
                              : (W2s + (size_t)(m-5)*HH*HH);
    float w = W[k*HH + n];
    short hi = f2bf(w);
    short lo = f2bf(w - bf2f(hi));
    short* base = Wp + (size_t)m*32768;
    base[r] = hi;
    base[16384 + r] = lo;
}

// ---------------- layer 0 (in=3) ----------------
__global__ void k_agg3(const float* __restrict__ x, const int* __restrict__ rp,
                       const int* __restrict__ ssrc, float* __restrict__ y){
    int i = blockIdx.x*256 + threadIdx.x;
    if (i >= NN) return;
    float a0 = x[3*i], a1 = x[3*i+1], a2 = x[3*i+2];
    int b = rp[i], e = rp[i+1];
    for (int k = b; k < e; k++){
        int s = ssrc[k];
        a0 += x[3*s]; a1 += x[3*s+1]; a2 += x[3*s+2];
    }
    y[3*i] = a0; y[3*i+1] = a1; y[3*i+2] = a2;
}

__global__ void k_mlp0(const float* __restrict__ y0, const float* __restrict__ W1,
                       const float* __restrict__ b1, const float* __restrict__ g,
                       const float* __restrict__ be, const float* __restrict__ m,
                       const float* __restrict__ v, float* __restrict__ out){
    int idx = blockIdx.x*256 + threadIdx.x;
    if (idx >= NN*HH) return;
    int i = idx >> 7, j = idx & 127;
    float acc = b1[j] + y0[3*i]*W1[j] + y0[3*i+1]*W1[HH+j] + y0[3*i+2]*W1[2*HH+j];
    float r = rsqrtf(v[j] + 1e-5f);
    acc = g[j]*(acc - m[j])*r + be[j];
    out[idx] = fmaxf(acc, 0.f);
}

// ---------------- aggregation: y[i] = h[i] + sum_{e in CSR[i]} h[src_e]
// half-wave (32 lanes) per node; 4-way unrolled edge loop with independent
// accumulators -> 4 x 512B gathers in flight per trip (MLP, latency hiding)
__global__ void k_agg(const float* __restrict__ h, const int* __restrict__ rp,
                      const int* __restrict__ ssrc, float* __restrict__ y){
    int node = blockIdx.x*8 + (threadIdx.x >> 5);
    if (node >= NN) return;
    int c = (threadIdx.x & 31) << 2;
    const float* hc = h + c;
    int b = rp[node], e = rp[node+1];
    float4 a0 = *(const float4*)&hc[(size_t)node*HH];
    float4 a1 = {0,0,0,0}, a2 = {0,0,0,0}, a3 = {0,0,0,0};
    int k = b;
    for (; k + 3 < e; k += 4){
        int s0 = ssrc[k], s1 = ssrc[k+1], s2 = ssrc[k+2], s3 = ssrc[k+3];
        float4 t0 = *(const float4*)&hc[(size_t)s0*HH];
        float4 t1 = *(const float4*)&hc[(size_t)s1*HH];
        float4 t2 = *(const float4*)&hc[(size_t)s2*HH];
        float4 t3 = *(const float4*)&hc[(size_t)s3*HH];
        a0.x+=t0.x; a0.y+=t0.y; a0.z+=t0.z; a0.w+=t0.w;
        a1.x+=t1.x; a1.y+=t1.y; a1.z+=t1.z; a1.w+=t1.w;
        a2.x+=t2.x; a2.y+=t2.y; a2.z+=t2.z; a2.w+=t2.w;
        a3.x+=t3.x; a3.y+=t3.y; a3.z+=t3.z; a3.w+=t3.w;
    }
    if (k + 1 < e){
        int s0 = ssrc[k], s1 = ssrc[k+1];
        float4 t0 = *(const float4*)&hc[(size_t)s0*HH];
        float4 t1 = *(const float4*)&hc[(size_t)s1*HH];
        a0.x+=t0.x; a0.y+=t0.y; a0.z+=t0.z; a0.w+=t0.w;
        a1.x+=t1.x; a1.y+=t1.y; a1.z+=t1.z; a1.w+=t1.w;
        k += 2;
    }
    if (k < e){
        int s0 = ssrc[k];
        float4 t0 = *(const float4*)&hc[(size_t)s0*HH];
        a0.x+=t0.x; a0.y+=t0.y; a0.z+=t0.z; a0.w+=t0.w;
    }
    a0.x += a1.x+a2.x+a3.x; a0.y += a1.y+a2.y+a3.y;
    a0.z += a1.z+a2.z+a3.z; a0.w += a1.w+a2.w+a3.w;
    *(float4*)&y[(size_t)node*HH + c] = a0;
}

// ---------------- MFMA bf16x3 GEMM [NPAD,128] @ [128,128] + bias/BN/ReLU -----
// Truncation split: hi = bits[31:16] of x, lo = bits[31:16] of (x - hi).
// Residual captured to 2^-16 rel -- same accuracy class as RNE split, ~half
// the VALU ops.
__global__ void k_gemm_mfma(const float* __restrict__ A, const short* __restrict__ Wp,
                            const float* __restrict__ bias, const float* __restrict__ g,
                            const float* __restrict__ be, const float* __restrict__ m,
                            const float* __restrict__ v, int use_bn,
                            float* __restrict__ out){
    int t = threadIdx.x;
    int l = t & 63, w = t >> 6;
    int n = l & 15, q = l >> 4;
    int R = blockIdx.x*128 + w*32;

    const float* a0p = A + (size_t)(R + n)*HH + q*8;
    const float* a1p = a0p + (size_t)16*HH;
    const short* Wh = Wp;
    const short* Wl = Wp + 16384;

    f32x4 acc[2][8];
#pragma unroll
    for (int rt = 0; rt < 2; rt++)
#pragma unroll
        for (int ct = 0; ct < 8; ct++) acc[rt][ct] = (f32x4){0.f,0.f,0.f,0.f};

#pragma unroll
    for (int kc = 0; kc < 4; kc++){
        float4 f0a = *(const float4*)(a0p + kc*32);
        float4 f0b = *(const float4*)(a0p + kc*32 + 4);
        float4 f1a = *(const float4*)(a1p + kc*32);
        float4 f1b = *(const float4*)(a1p + kc*32 + 4);
        float x0[8] = {f0a.x,f0a.y,f0a.z,f0a.w,f0b.x,f0b.y,f0b.z,f0b.w};
        float x1[8] = {f1a.x,f1a.y,f1a.z,f1a.w,f1b.x,f1b.y,f1b.z,f1b.w};
        bf16x8 ah0, al0, ah1, al1;
#pragma unroll
        for (int i = 0; i < 8; i++){
            unsigned u0 = __float_as_uint(x0[i]);
            ah0[i] = (short)(u0 >> 16);
            float r0 = x0[i] - __uint_as_float(u0 & 0xFFFF0000u);
            al0[i] = (short)(__float_as_uint(r0) >> 16);
            unsigned u1 = __float_as_uint(x1[i]);
            ah1[i] = (short)(u1 >> 16);
            float r1 = x1[i] - __uint_as_float(u1 & 0xFFFF0000u);
            al1[i] = (short)(__float_as_uint(r1) >> 16);
        }
        const short* ph = Wh + (size_t)(kc*8)*512 + l*8;
        const short* pl = Wl + (size_t)(kc*8)*512 + l*8;
#pragma unroll
        for (int ct = 0; ct < 8; ct++){
            bf16x8 bh = *(const bf16x8*)(ph + ct*512);
            bf16x8 bl = *(const bf16x8*)(pl + ct*512);
            acc[0][ct] = __builtin_amdgcn_mfma_f32_16x16x32_bf16(ah0, bh, acc[0][ct], 0, 0, 0);
            acc[1][ct] = __builtin_amdgcn_mfma_f32_16x16x32_bf16(ah1, bh, acc[1][ct], 0, 0, 0);
            acc[0][ct] = __builtin_amdgcn_mfma_f32_16x16x32_bf16(al0, bh, acc[0][ct], 0, 0, 0);
            acc[1][ct] = __builtin_amdgcn_mfma_f32_16x16x32_bf16(al1, bh, acc[1][ct], 0, 0, 0);
            acc[0][ct] = __builtin_amdgcn_mfma_f32_16x16x32_bf16(ah0, bl, acc[0][ct], 0, 0, 0);
            acc[1][ct] = __builtin_amdgcn_mfma_f32_16x16x32_bf16(ah1, bl, acc[1][ct], 0, 0, 0);
        }
    }

    // epilogue: out = relu(sc*acc + sh)
#pragma unroll
    for (int ct = 0; ct < 8; ct++){
        int j = (ct << 4) + n;
        float scv, shv;
        if (use_bn){
            float rr = rsqrtf(v[j] + 1e-5f);
            float gg = g[j]*rr;
            scv = gg;
            shv = be[j] + gg*(bias[j] - m[j]);
        } else {
            scv = 1.f;
            shv = bias[j];
        }
#pragma unroll
        for (int rt = 0; rt < 2; rt++){
#pragma unroll
            for (int r = 0; r < 4; r++){
                int row = R + rt*16 + q*4 + r;
                out[(size_t)row*HH + j] = fmaxf(fmaf(acc[rt][ct][r], scv, shv), 0.f);
            }
        }
    }
}

// ---------------- pooling + classifier: block per graph, no atomics ---------
__global__ void k_pool2(const float* __restrict__ h, const float* __restrict__ Wc,
                        const float* __restrict__ bc, const int* __restrict__ rp_g,
                        float* __restrict__ out){
    __shared__ float ws[4];
    int g = blockIdx.x, t = threadIdx.x;
    long beg = (long)rp_g[g]*HH, end = (long)rp_g[g+1]*HH;
    float s = 0.f;
    for (long i = beg + t; i < end; i += 256) s += h[i]*Wc[(int)(i & 127)];
    int lane = t & 63, w = t >> 6;
#pragma unroll
    for (int off = 32; off > 0; off >>= 1) s += __shfl_down(s, off);
    if (lane == 0) ws[w] = s;
    __syncthreads();
    if (t == 0) out[g] = bc[0] + ws[0] + ws[1] + ws[2] + ws[3];
}

extern "C" void kernel_launch(void* const* d_in, const int* in_sizes, int n_in,
                              void* d_out, int out_size, void* d_ws, size_t ws_size,
                              hipStream_t stream){
    const float* x     = (const float*)d_in[0];
    const int*   ei    = (const int*)d_in[1];
    const int*   batch = (const int*)d_in[2];
    const float* W1_0  = (const float*)d_in[3];
    const float* b1_0  = (const float*)d_in[4];
    const float* g_0   = (const float*)d_in[5];
    const float* be_0  = (const float*)d_in[6];
    const float* m_0   = (const float*)d_in[7];
    const float* v_0   = (const float*)d_in[8];
    const float* W2_0  = (const float*)d_in[9];
    const float* b2_0  = (const float*)d_in[10];
    const float* W1s   = (const float*)d_in[11];
    const float* b1s   = (const float*)d_in[12];
    const float* gs    = (const float*)d_in[13];
    const float* bes   = (const float*)d_in[14];
    const float* ms    = (const float*)d_in[15];
    const float* vs    = (const float*)d_in[16];
    const float* W2s   = (const float*)d_in[17];
    const float* b2s   = (const float*)d_in[18];
    const float* Wc    = (const float*)d_in[19];
    const float* bc    = (const float*)d_in[20];

    float* P0 = (float*)d_ws;
    float* P1 = P0 + (size_t)NPAD*HH;
    int* rp    = (int*)(P1 + (size_t)NPAD*HH);
    int* fill  = rp + (NN + 1);
    int* ssrc  = fill + NN;
    int* bsums = ssrc + EE;
    int* rp_g  = bsums + 128;
    size_t wp_off = (size_t)(rp_g + (GG + 1) - (int*)d_ws);
    wp_off = (wp_off + 3) & ~(size_t)3;
    short* Wp = (short*)((int*)d_ws + wp_off);

    const int* src = ei;
    const int* dst = ei + EE;

    // --- CSR build ---
    k_zero_i32<<<(NN+255)/256, 256, 0, stream>>>(fill, NN);
    k_hist<<<(EE+255)/256, 256, 0, stream>>>(dst, fill);
    k_scan1<<<98, 256, 0, stream>>>(fill, rp, bsums, NN);
    k_scan2<<<1, 128, 0, stream>>>(bsums, 98);
    k_scan3<<<(NN+255)/256, 256, 0, stream>>>(rp, bsums, fill, NN);
    k_place<<<(EE+255)/256, 256, 0, stream>>>(src, dst, fill, ssrc);

    // --- graph rowptr + weight pre-swizzle ---
    k_bounds<<<(NN+255)/256, 256, 0, stream>>>(batch, rp_g);
    k_wprep<<<(9*16384)/256, 256, 0, stream>>>(W2_0, W1s, W2s, Wp);

    // --- layer 0 (in=3) ---
    k_agg3<<<(NN+255)/256, 256, 0, stream>>>(x, rp, ssrc, P0);
    k_mlp0<<<(NN*HH)/256, 256, 0, stream>>>(P0, W1_0, b1_0, g_0, be_0, m_0, v_0, P1);
    k_gemm_mfma<<<NBLK, 256, 0, stream>>>(P1, Wp, b2_0,
                                          nullptr, nullptr, nullptr, nullptr, 0, P0);

    // --- layers 1..4 ---
    float* cur = P0; float* oth = P1;
    for (int l = 0; l < 4; l++){
        k_agg<<<(NN+7)/8, 256, 0, stream>>>(cur, rp, ssrc, oth);
        k_gemm_mfma<<<NBLK, 256, 0, stream>>>(oth, Wp + (size_t)(1+l)*32768, b1s + l*HH,
                                              gs + l*HH, bes + l*HH, ms + l*HH, vs + l*HH,
                                              1, cur);
        k_gemm_mfma<<<NBLK, 256, 0, stream>>>(cur, Wp + (size_t)(5+l)*32768, b2s + l*HH,
                                              nullptr, nullptr, nullptr, nullptr, 0, oth);
        float* tmp = cur; cur = oth; oth = tmp;
    }

    // --- pooling + classifier (no atomics) ---
    k_pool2<<<GG, 256, 0, stream>>>(cur, Wc, bc, rp_g, (float*)d_out);
}